// Round 9
// baseline (3292.961 us; speedup 1.0000x reference)
//
#include <hip/hip_runtime.h>
#include <hip/hip_bf16.h>

typedef unsigned short u16;
typedef __attribute__((ext_vector_type(8))) short bf16x8;
typedef __attribute__((ext_vector_type(4))) float f32x4;

#define DEVINL __device__ __forceinline__

DEVINL u16 f2b(float f) {
    __hip_bfloat16 h = __float2bfloat16(f);
    return __builtin_bit_cast(u16, h);
}
DEVINL float b2f(u16 u) {
    unsigned int x = ((unsigned int)u) << 16;
    return __builtin_bit_cast(float, x);
}
DEVINL int iabs(int x) { return x < 0 ? -x : x; }
DEVINL f32x4 MFMA(bf16x8 a, bf16x8 b, f32x4 c) {
    return __builtin_amdgcn_mfma_f32_16x16x32_bf16(a, b, c, 0, 0, 0);
}

#define GL2LDS(g, s)                                                                     \
    __builtin_amdgcn_global_load_lds(                                                    \
        (const __attribute__((address_space(1))) unsigned int*)(g),                      \
        (__attribute__((address_space(3))) unsigned int*)(s), 16, 0, 0)

// ---------------------------------------------------------------------------
// Weight convert + transpose.
// z<3 (wq,wk,wv): w[k][n] f32, n = head*64+d  ->  wqkvt[head*192 + z*64 + d][k] bf16
// z==3 (wo): wot[n][k] bf16 (plain B^T)
// ---------------------------------------------------------------------------
__global__ __launch_bounds__(256) void wconv_kernel(const float* __restrict__ wq,
                                                    const float* __restrict__ wk,
                                                    const float* __restrict__ wv,
                                                    const float* __restrict__ wo,
                                                    u16* __restrict__ wqkvt,
                                                    u16* __restrict__ wot) {
    __shared__ float tile[32][33];
    int z = blockIdx.z;
    const float* src = (z == 0) ? wq : (z == 1) ? wk : (z == 2) ? wv : wo;
    int n0 = blockIdx.x * 32, k0 = blockIdx.y * 32;
    int r0 = threadIdx.x >> 5, c = threadIdx.x & 31;
#pragma unroll
    for (int i = 0; i < 4; i++) {
        int r = r0 + i * 8;
        tile[r][c] = src[(size_t)(k0 + r) * 1024 + n0 + c];
    }
    __syncthreads();
    u16* dst = (z < 3) ? wqkvt : wot;
#pragma unroll
    for (int i = 0; i < 4; i++) {
        int r = r0 + i * 8;
        int nn = n0 + r;
        size_t drow = (z < 3) ? ((size_t)(nn >> 6) * 192 + (size_t)z * 64 + (nn & 63))
                              : (size_t)nn;
        dst[drow * 1024 + k0 + c] = f2b(tile[c][r]);
    }
}

// ---------------------------------------------------------------------------
// LayerNorm: one wave per 1024-elem row, output bf16
// ---------------------------------------------------------------------------
__global__ __launch_bounds__(256) void ln_kernel(const float* __restrict__ x,
                                                 const float* __restrict__ gamma,
                                                 const float* __restrict__ beta,
                                                 u16* __restrict__ h) {
    int w = threadIdx.x >> 6, l = threadIdx.x & 63;
    size_t row = (size_t)blockIdx.x * 4 + w;
    const float4* xr = (const float4*)(x + row * 1024);
    float4 v[4];
    float s = 0.f, sq = 0.f;
#pragma unroll
    for (int i = 0; i < 4; i++) {
        v[i] = xr[l + i * 64];
        s += v[i].x + v[i].y + v[i].z + v[i].w;
        sq += v[i].x * v[i].x + v[i].y * v[i].y + v[i].z * v[i].z + v[i].w * v[i].w;
    }
#pragma unroll
    for (int off = 1; off < 64; off <<= 1) {
        s += __shfl_xor(s, off);
        sq += __shfl_xor(sq, off);
    }
    float mu = s * (1.f / 1024.f);
    float var = sq * (1.f / 1024.f) - mu * mu;
    float rstd = rsqrtf(var + 1e-5f);
    const float4* g4 = (const float4*)gamma;
    const float4* b4 = (const float4*)beta;
#pragma unroll
    for (int i = 0; i < 4; i++) {
        float4 g = g4[l + i * 64], b = b4[l + i * 64];
        float y0 = (v[i].x - mu) * rstd * g.x + b.x;
        float y1 = (v[i].y - mu) * rstd * g.y + b.y;
        float y2 = (v[i].z - mu) * rstd * g.z + b.z;
        float y3 = (v[i].w - mu) * rstd * g.w + b.w;
        unsigned int lo = (unsigned int)f2b(y0) | ((unsigned int)f2b(y1) << 16);
        unsigned int hi = (unsigned int)f2b(y2) | ((unsigned int)f2b(y3) << 16);
        uint2 pk;
        pk.x = lo;
        pk.y = hi;
        *(uint2*)(h + row * 1024 + (size_t)(l + i * 64) * 4) = pk;
    }
}

// ---------------------------------------------------------------------------
// Fused QKV-projection + attention, M=224 (8 seqs) x 192 cols (one head).
// 512 threads, 8 waves (2M x 4N): wave wm=w>>2 covers 112 rows, wn=w&3 covers
// 48 cols; 7x3 frags/wave. AI = 103 FLOP/staged-byte (R9 fix for the staging-
// bandwidth wall measured in R8: was 35).
// LDS = 53248 B -> 3 blocks/CU.
//   GEMM: sA [0,28672) = 224 rows x 128B (chunk 3 by t<256); sB [28672,53248).
//   Attn epilogue in TWO half-passes (h=0: rows 0-111/seqs 0-3, h=1: rows
//   112-223/seqs 4-7), each 4 phases:
//     P1 (wm==h waves): q,k acc -> qkb swizzled [112][128] u16 @0 (28672B).
//     P2 (ALL waves): wave w = (seq w>>1, i-half w&1): 4 QK^T MFMAs, softmax
//        of 16 rows, P -> sp[w] u16[16][40] @28672+w*1280 (10240B total).
//     P3 (wm==h waves): v acc -> vt u16[4][64][40] @0 over dead qkb (20480B).
//     P4 (ALL waves): 4 PV MFMAs, ctx write (dense [57344][1024]).
//   Garbage audit: A-rows beyond seq end -> score rows i>=28 (discarded);
//   b1 rows beyond qkb (sp region) occur only at j>=28 (masked to -1e30).
// ---------------------------------------------------------------------------
__global__ __launch_bounds__(512, 6) void fused_qkv_attn(const u16* __restrict__ h,
                                                         const u16* __restrict__ wqkvt,
                                                         u16* __restrict__ ctx) {
    __shared__ __align__(16) char smem[53248];
    char* sA = smem;
    char* sB = smem + 28672;
    int t = threadIdx.x;

    int nwg = gridDim.x;  // 4096
    int cpx = nwg >> 3;
    int wg = ((int)blockIdx.x & 7) * cpx + ((int)blockIdx.x >> 3);
    int x = wg >> 9;                 // XCD 0..7
    int i0 = wg & 511;
    int bm = i0 >> 1;                // 0..255 (fast)
    int head = (x << 1) | (i0 & 1);  // 0..15

    // staging: 512 threads cover 64 rows (8192B) per chunk; XOR swizzle on source
    int p16 = t * 16;
    int srow = p16 >> 7;  // 0..63
    int scolb = (p16 & 127) ^ ((srow & 7) << 4);
    const char* aB = (const char*)h + ((size_t)bm * 224 + srow) * 2048 + scolb;
    const char* bB = (const char*)wqkvt + ((size_t)head * 192 + srow) * 2048 + scolb;

    int l = t & 63, w = t >> 6, g = l >> 4, lr = l & 15;
    int wm = w >> 2, wn = w & 3;
    int swz = (lr & 7) << 4;

    f32x4 acc[7][3];
#pragma unroll
    for (int m = 0; m < 7; m++)
#pragma unroll
        for (int n = 0; n < 3; n++) acc[m][n] = {0.f, 0.f, 0.f, 0.f};

#pragma unroll 1
    for (int kt = 0; kt < 16; ++kt) {
        int kb = kt * 128;
#pragma unroll
        for (int i = 0; i < 3; i++) GL2LDS(aB + (size_t)i * 131072 + kb, sA + i * 8192 + p16);
        if (t < 256) GL2LDS(aB + (size_t)3 * 131072 + kb, sA + 3 * 8192 + p16);
#pragma unroll
        for (int i = 0; i < 3; i++) GL2LDS(bB + (size_t)i * 131072 + kb, sB + i * 8192 + p16);
        __syncthreads();
#pragma unroll
        for (int ks = 0; ks < 2; ++ks) {
            bf16x8 af[7], bfv[3];
#pragma unroll
            for (int m = 0; m < 7; m++)
                af[m] = *(const bf16x8*)(sA + (wm * 112 + m * 16 + lr) * 128 +
                                         ((ks * 64 + g * 16) ^ swz));
#pragma unroll
            for (int n = 0; n < 3; n++)
                bfv[n] = *(const bf16x8*)(sB + (wn * 48 + n * 16 + lr) * 128 +
                                          ((ks * 64 + g * 16) ^ swz));
#pragma unroll
            for (int m = 0; m < 7; m++)
#pragma unroll
                for (int n = 0; n < 3; n++) acc[m][n] = MFMA(af[m], bfv[n], acc[m][n]);
        }
        __syncthreads();
    }

    // ---------------- attention epilogue: two half-passes ----------------
    u16* qkb = (u16*)smem;                       // [112][128] swizzled
    u16(*vt)[64][40] = (u16(*)[64][40])smem;     // phase-3 alias (20480B)
    u16(*spw)[40] = (u16(*)[40])(smem + 28672 + w * 1280);  // this wave's P [16][40]

    int sl = w >> 1, ih = w & 1;    // seq-local 0..3, i-half 0..1
    int rb = sl * 28;
    float slope = exp2f(-0.5f * (float)(head + 1));
    int j0 = lr, j1 = 16 + lr;
    int j0m = j0 % 14, j0d = j0 / 14;
    int j1m = j1 % 14, j1d = j1 / 14;

#pragma unroll 1
    for (int hh = 0; hh < 2; ++hh) {
        // ---- P1: q,k -> swizzled qkb (waves holding rows of this half) ----
        if (wm == hh) {
#pragma unroll
            for (int m = 0; m < 7; m++)
#pragma unroll
                for (int n = 0; n < 3; n++) {
                    int col = wn * 48 + n * 16 + lr;
                    if (col < 128) {
#pragma unroll
                        for (int r = 0; r < 4; ++r) {
                            int lrow = m * 16 + g * 4 + r;
                            qkb[lrow * 128 + (col ^ ((lrow & 7) << 3))] = f2b(acc[m][n][r]);
                        }
                    }
                }
        }
        __syncthreads();

        // ---- P2: QK^T (4 MFMAs) + softmax of 16 rows ----
        f32x4 sc0 = {0.f, 0.f, 0.f, 0.f}, sc1 = {0.f, 0.f, 0.f, 0.f};
#pragma unroll
        for (int c = 0; c < 2; ++c) {
            int u0 = c * 32 + g * 8;
            int arow = rb + ih * 16 + lr;
            int br0 = rb + lr, br1 = rb + 16 + lr;
            bf16x8 aa = *(const bf16x8*)&qkb[arow * 128 + (u0 ^ ((arow & 7) << 3))];
            bf16x8 b0 = *(const bf16x8*)&qkb[br0 * 128 + ((64 + u0) ^ ((br0 & 7) << 3))];
            bf16x8 b1 = *(const bf16x8*)&qkb[br1 * 128 + ((64 + u0) ^ ((br1 & 7) << 3))];
            sc0 = MFMA(aa, b0, sc0);
            sc1 = MFMA(aa, b1, sc1);
        }
#pragma unroll
        for (int r = 0; r < 4; ++r) {
            int i = ih * 16 + g * 4 + r;
            int im = i % 14, id = i / 14;
            float s0 = sc0[r] + slope * (float)(iabs(im - j0m) + iabs(id - j0d));
            float s1 = (j1 < 28)
                           ? sc1[r] + slope * (float)(iabs(im - j1m) + iabs(id - j1d))
                           : -1e30f;
            float mx = fmaxf(s0, s1);
#pragma unroll
            for (int off = 1; off < 16; off <<= 1) mx = fmaxf(mx, __shfl_xor(mx, off));
            float e0 = __expf(s0 - mx), e1 = __expf(s1 - mx);
            float sm = e0 + e1;
#pragma unroll
            for (int off = 1; off < 16; off <<= 1) sm += __shfl_xor(sm, off);
            float inv = 1.f / sm;
            spw[g * 4 + r][lr] = f2b(e0 * inv);
            spw[g * 4 + r][16 + lr] = f2b(e1 * inv);
        }
        __syncthreads();  // all qkb reads done -> region reusable for vt

        // ---- P3: v -> vt over dead qkb ----
        if (t < 256) {
            int s2 = t >> 6, d = t & 63;
#pragma unroll
            for (int j = 28; j < 32; ++j) vt[s2][d][j] = 0;
        }
        if (wm == hh) {
#pragma unroll
            for (int m = 0; m < 7; m++)
#pragma unroll
                for (int n = 0; n < 3; n++) {
                    int col = wn * 48 + n * 16 + lr;
                    if (col >= 128) {
#pragma unroll
                        for (int r = 0; r < 4; ++r) {
                            int lrow = m * 16 + g * 4 + r;
                            int d = col - 128;
                            int s2 = lrow / 28;
                            int j = lrow - s2 * 28;
                            vt[s2][d][j] = f2b(acc[m][n][r]);
                        }
                    }
                }
        }
        __syncthreads();

        // ---- P4: PV (4 MFMAs) + ctx write ----
        bf16x8 pa = *(const bf16x8*)&spw[lr][g * 8];
        f32x4 o[4];
#pragma unroll
        for (int d = 0; d < 4; d++) o[d] = {0.f, 0.f, 0.f, 0.f};
#pragma unroll
        for (int dt = 0; dt < 4; ++dt) {
            bf16x8 bv = *(const bf16x8*)&vt[sl][dt * 16 + lr][g * 8];
            o[dt] = MFMA(pa, bv, o[dt]);
        }
#pragma unroll
        for (int dt = 0; dt < 4; ++dt)
#pragma unroll
            for (int r = 0; r < 4; ++r) {
                int i = ih * 16 + g * 4 + r;
                if (i < 28) {
                    size_t grow = (size_t)bm * 224 + (size_t)hh * 112 + sl * 28 + i;
                    ctx[grow * 1024 + head * 64 + dt * 16 + lr] = f2b(o[dt][r]);
                }
            }
        __syncthreads();  // before next half overwrites qkb
    }
}

// ---------------------------------------------------------------------------
// GEMM (round-1 verbatim): C[M,N] = A[M,1024] bf16 x Bt[N,1024] bf16.
// 128x128 tile, BK=64x2, 256 threads. Used for the output projection.
// ---------------------------------------------------------------------------
template <int OUT_BF16, int RESID>
__global__ __launch_bounds__(256, 2) void gemm_bt(const u16* __restrict__ A,
                                                  const u16* __restrict__ Bt,
                                                  void* __restrict__ Cv,
                                                  const u16* __restrict__ resid,
                                                  int lda, int ldc) {
    __shared__ u16 smem[16384];
    int t = threadIdx.x;

    int nwg = gridDim.x;
    int cpx = nwg >> 3;
    int wg = (blockIdx.x & 7) * cpx + (blockIdx.x >> 3);
    const int sgrp = 448 * 8;
    int sn = wg / sgrp;
    int rem = wg - sn * sgrp;
    int bm = rem >> 3;
    int bn = sn * 8 + (rem & 7);

    const char* Ab = (const char*)A;
    const char* Bb = (const char*)Bt;
    size_t aoffg[4], boffg[4];
#pragma unroll
    for (int i = 0; i < 4; i++) {
        int p = t * 16 + i * 4096;
        int row = p >> 7;
        int colb = (p & 127) ^ ((row & 7) << 4);
        aoffg[i] = (size_t)(bm * 128 + row) * (size_t)lda * 2 + colb;
        boffg[i] = (size_t)(bn * 128 + row) * 2048 + colb;
    }
    char* sA = (char*)smem;
    char* sB = sA + 16384;

    int l = t & 63, w = t >> 6;
    int wm = w >> 1, wn = w & 1, g = l >> 4, lr = l & 15;
    int swz = (lr & 7) << 4;

    f32x4 acc[4][4];
#pragma unroll
    for (int m = 0; m < 4; m++)
#pragma unroll
        for (int n = 0; n < 4; n++) acc[m][n] = {0.f, 0.f, 0.f, 0.f};

    for (int kt = 0; kt < 16; ++kt) {
        int kb = kt * 128;
#pragma unroll
        for (int i = 0; i < 4; i++) GL2LDS(Ab + aoffg[i] + kb, sA + i * 4096 + t * 16);
#pragma unroll
        for (int i = 0; i < 4; i++) GL2LDS(Bb + boffg[i] + kb, sB + i * 4096 + t * 16);
        __syncthreads();
#pragma unroll
        for (int ks = 0; ks < 2; ++ks) {
            bf16x8 af[4], bfv[4];
#pragma unroll
            for (int m = 0; m < 4; m++)
                af[m] = *(const bf16x8*)(sA + (wm * 64 + m * 16 + lr) * 128 +
                                         ((ks * 64 + g * 16) ^ swz));
#pragma unroll
            for (int n = 0; n < 4; n++)
                bfv[n] = *(const bf16x8*)(sB + (wn * 64 + n * 16 + lr) * 128 +
                                          ((ks * 64 + g * 16) ^ swz));
#pragma unroll
            for (int m = 0; m < 4; m++)
#pragma unroll
                for (int n = 0; n < 4; n++)
                    acc[m][n] = MFMA(af[m], bfv[n], acc[m][n]);
        }
        __syncthreads();
    }

    size_t row0 = (size_t)bm * 128 + wm * 64;
    int col0 = bn * 128 + wn * 64;
    if (OUT_BF16) {
        u16* C = (u16*)Cv;
#pragma unroll
        for (int m = 0; m < 4; m++)
#pragma unroll
            for (int n = 0; n < 4; n++)
#pragma unroll
                for (int r = 0; r < 4; r++) {
                    size_t rr = row0 + m * 16 + g * 4 + r;
                    int cc = col0 + n * 16 + lr;
                    C[rr * (size_t)ldc + cc] = f2b(acc[m][n][r]);
                }
    } else {
        float* C = (float*)Cv;
#pragma unroll
        for (int m = 0; m < 4; m++)
#pragma unroll
            for (int n = 0; n < 4; n++)
#pragma unroll
                for (int r = 0; r < 4; r++) {
                    size_t rr = row0 + m * 16 + g * 4 + r;
                    int cc = col0 + n * 16 + lr;
                    float o = acc[m][n][r];
                    if (RESID) o += b2f(resid[rr * 1024 + cc]);
                    C[rr * (size_t)ldc + cc] = o;
                }
    }
}

// ---------------------------------------------------------------------------
extern "C" void kernel_launch(void* const* d_in, const int* in_sizes, int n_in,
                              void* d_out, int out_size, void* d_ws, size_t ws_size,
                              hipStream_t stream) {
    (void)in_sizes; (void)n_in; (void)out_size; (void)ws_size;
    const float* hidden = (const float*)d_in[0];
    const float* wq = (const float*)d_in[1];
    const float* wk = (const float*)d_in[2];
    const float* wv = (const float*)d_in[3];
    const float* wo = (const float*)d_in[4];
    const float* gamma = (const float*)d_in[5];
    const float* beta = (const float*)d_in[6];
    float* out = (float*)d_out;

    char* ws = (char*)d_ws;
    u16* h = (u16*)ws;                                  // 117,440,512 B
    u16* ctx = (u16*)(ws + 117440512);                  // 117,440,512 B
    u16* wqkvt = (u16*)(ws + 234881024);                //   6,291,456 B
    u16* wot = (u16*)(ws + 234881024 + 6291456);        //   2,097,152 B

    wconv_kernel<<<dim3(32, 32, 4), 256, 0, stream>>>(wq, wk, wv, wo, wqkvt, wot);
    ln_kernel<<<14336, 256, 0, stream>>>(hidden, gamma, beta, h);
    fused_qkv_attn<<<4096, 512, 0, stream>>>(h, wqkvt, ctx);
    // ctx is dense [57344][1024] -> lda = 1024
    gemm_bt<0, 1><<<448 * 8, 256, 0, stream>>>(ctx, wot, out, h, 1024, 1024);
}

// Round 10
// 776.919 us; speedup vs baseline: 4.2385x; 4.2385x over previous
//
#include <hip/hip_runtime.h>
#include <hip/hip_bf16.h>

typedef unsigned short u16;
typedef __attribute__((ext_vector_type(8))) short bf16x8;
typedef __attribute__((ext_vector_type(4))) float f32x4;

#define DEVINL __device__ __forceinline__

DEVINL u16 f2b(float f) {
    __hip_bfloat16 h = __float2bfloat16(f);
    return __builtin_bit_cast(u16, h);
}
DEVINL float b2f(u16 u) {
    unsigned int x = ((unsigned int)u) << 16;
    return __builtin_bit_cast(float, x);
}
DEVINL int iabs(int x) { return x < 0 ? -x : x; }
DEVINL f32x4 MFMA(bf16x8 a, bf16x8 b, f32x4 c) {
    return __builtin_amdgcn_mfma_f32_16x16x32_bf16(a, b, c, 0, 0, 0);
}

#define GL2LDS(g, s)                                                                     \
    __builtin_amdgcn_global_load_lds(                                                    \
        (const __attribute__((address_space(1))) unsigned int*)(g),                      \
        (__attribute__((address_space(3))) unsigned int*)(s), 16, 0, 0)

// ---------------------------------------------------------------------------
// Weight convert + transpose.
// z<3 (wq,wk,wv): w[k][n] f32, n = head*64+d  ->  wqkvt[head*192 + z*64 + d][k] bf16
// z==3 (wo): wot[n][k] bf16 (plain B^T)
// ---------------------------------------------------------------------------
__global__ __launch_bounds__(256) void wconv_kernel(const float* __restrict__ wq,
                                                    const float* __restrict__ wk,
                                                    const float* __restrict__ wv,
                                                    const float* __restrict__ wo,
                                                    u16* __restrict__ wqkvt,
                                                    u16* __restrict__ wot) {
    __shared__ float tile[32][33];
    int z = blockIdx.z;
    const float* src = (z == 0) ? wq : (z == 1) ? wk : (z == 2) ? wv : wo;
    int n0 = blockIdx.x * 32, k0 = blockIdx.y * 32;
    int r0 = threadIdx.x >> 5, c = threadIdx.x & 31;
#pragma unroll
    for (int i = 0; i < 4; i++) {
        int r = r0 + i * 8;
        tile[r][c] = src[(size_t)(k0 + r) * 1024 + n0 + c];
    }
    __syncthreads();
    u16* dst = (z < 3) ? wqkvt : wot;
#pragma unroll
    for (int i = 0; i < 4; i++) {
        int r = r0 + i * 8;
        int nn = n0 + r;
        size_t drow = (z < 3) ? ((size_t)(nn >> 6) * 192 + (size_t)z * 64 + (nn & 63))
                              : (size_t)nn;
        dst[drow * 1024 + k0 + c] = f2b(tile[c][r]);
    }
}

// ---------------------------------------------------------------------------
// LayerNorm: one wave per 1024-elem row, output bf16
// ---------------------------------------------------------------------------
__global__ __launch_bounds__(256) void ln_kernel(const float* __restrict__ x,
                                                 const float* __restrict__ gamma,
                                                 const float* __restrict__ beta,
                                                 u16* __restrict__ h) {
    int w = threadIdx.x >> 6, l = threadIdx.x & 63;
    size_t row = (size_t)blockIdx.x * 4 + w;
    const float4* xr = (const float4*)(x + row * 1024);
    float4 v[4];
    float s = 0.f, sq = 0.f;
#pragma unroll
    for (int i = 0; i < 4; i++) {
        v[i] = xr[l + i * 64];
        s += v[i].x + v[i].y + v[i].z + v[i].w;
        sq += v[i].x * v[i].x + v[i].y * v[i].y + v[i].z * v[i].z + v[i].w * v[i].w;
    }
#pragma unroll
    for (int off = 1; off < 64; off <<= 1) {
        s += __shfl_xor(s, off);
        sq += __shfl_xor(sq, off);
    }
    float mu = s * (1.f / 1024.f);
    float var = sq * (1.f / 1024.f) - mu * mu;
    float rstd = rsqrtf(var + 1e-5f);
    const float4* g4 = (const float4*)gamma;
    const float4* b4 = (const float4*)beta;
#pragma unroll
    for (int i = 0; i < 4; i++) {
        float4 g = g4[l + i * 64], b = b4[l + i * 64];
        float y0 = (v[i].x - mu) * rstd * g.x + b.x;
        float y1 = (v[i].y - mu) * rstd * g.y + b.y;
        float y2 = (v[i].z - mu) * rstd * g.z + b.z;
        float y3 = (v[i].w - mu) * rstd * g.w + b.w;
        unsigned int lo = (unsigned int)f2b(y0) | ((unsigned int)f2b(y1) << 16);
        unsigned int hi = (unsigned int)f2b(y2) | ((unsigned int)f2b(y3) << 16);
        uint2 pk;
        pk.x = lo;
        pk.y = hi;
        *(uint2*)(h + row * 1024 + (size_t)(l + i * 64) * 4) = pk;
    }
}

// ---------------------------------------------------------------------------
// Fused QKV-projection + attention, M=224 (8 seqs) x 192 cols (one head).
// 512 threads, 8 waves (2M x 4N); 7x3 frags/wave. AI = 103 FLOP/staged-byte.
// LDS = 53248 B. __launch_bounds__(512, 2): R10 fix — (512,6) capped the
// allocator at ~85 regs and spilled acc[7][3] to scratch (VGPR 40, 14.9 GB
// scratch traffic, 3.2 ms). Regs ~150/thread -> 1 block/CU; intra-block
// overlap only (R2 precedent: 44.6% util in this regime).
//   GEMM: sA [0,28672) = 224 rows x 128B (chunk 3 by t<256); sB [28672,53248).
//   Attn epilogue in TWO half-passes (h=0: rows 0-111/seqs 0-3, h=1: rows
//   112-223/seqs 4-7), each 4 phases:
//     P1 (wm==h waves): q,k acc -> qkb swizzled [112][128] u16 @0 (28672B).
//     P2 (ALL waves): wave w = (seq w>>1, i-half w&1): 4 QK^T MFMAs, softmax
//        of 16 rows, P -> sp[w] u16[16][40] @28672+w*1280 (10240B total).
//     P3 (wm==h waves): v acc -> vt u16[4][64][40] @0 over dead qkb (20480B).
//     P4 (ALL waves): 4 PV MFMAs, ctx write (dense [57344][1024]).
//   Garbage audit: A-rows beyond seq end -> score rows i>=28 (discarded);
//   b1 rows beyond qkb (sp region) occur only at j>=28 (masked to -1e30).
// ---------------------------------------------------------------------------
__global__ __launch_bounds__(512, 2) void fused_qkv_attn(const u16* __restrict__ h,
                                                         const u16* __restrict__ wqkvt,
                                                         u16* __restrict__ ctx) {
    __shared__ __align__(16) char smem[53248];
    char* sA = smem;
    char* sB = smem + 28672;
    int t = threadIdx.x;

    int nwg = gridDim.x;  // 4096
    int cpx = nwg >> 3;
    int wg = ((int)blockIdx.x & 7) * cpx + ((int)blockIdx.x >> 3);
    int x = wg >> 9;                 // XCD 0..7
    int i0 = wg & 511;
    int bm = i0 >> 1;                // 0..255 (fast)
    int head = (x << 1) | (i0 & 1);  // 0..15

    // staging: 512 threads cover 64 rows (8192B) per chunk; XOR swizzle on source
    int p16 = t * 16;
    int srow = p16 >> 7;  // 0..63
    int scolb = (p16 & 127) ^ ((srow & 7) << 4);
    const char* aB = (const char*)h + ((size_t)bm * 224 + srow) * 2048 + scolb;
    const char* bB = (const char*)wqkvt + ((size_t)head * 192 + srow) * 2048 + scolb;

    int l = t & 63, w = t >> 6, g = l >> 4, lr = l & 15;
    int wm = w >> 2, wn = w & 3;
    int swz = (lr & 7) << 4;

    f32x4 acc[7][3];
#pragma unroll
    for (int m = 0; m < 7; m++)
#pragma unroll
        for (int n = 0; n < 3; n++) acc[m][n] = {0.f, 0.f, 0.f, 0.f};

#pragma unroll 1
    for (int kt = 0; kt < 16; ++kt) {
        int kb = kt * 128;
#pragma unroll
        for (int i = 0; i < 3; i++) GL2LDS(aB + (size_t)i * 131072 + kb, sA + i * 8192 + p16);
        if (t < 256) GL2LDS(aB + (size_t)3 * 131072 + kb, sA + 3 * 8192 + p16);
#pragma unroll
        for (int i = 0; i < 3; i++) GL2LDS(bB + (size_t)i * 131072 + kb, sB + i * 8192 + p16);
        __syncthreads();
#pragma unroll
        for (int ks = 0; ks < 2; ++ks) {
            bf16x8 af[7], bfv[3];
#pragma unroll
            for (int m = 0; m < 7; m++)
                af[m] = *(const bf16x8*)(sA + (wm * 112 + m * 16 + lr) * 128 +
                                         ((ks * 64 + g * 16) ^ swz));
#pragma unroll
            for (int n = 0; n < 3; n++)
                bfv[n] = *(const bf16x8*)(sB + (wn * 48 + n * 16 + lr) * 128 +
                                          ((ks * 64 + g * 16) ^ swz));
#pragma unroll
            for (int m = 0; m < 7; m++)
#pragma unroll
                for (int n = 0; n < 3; n++) acc[m][n] = MFMA(af[m], bfv[n], acc[m][n]);
        }
        __syncthreads();
    }

    // ---------------- attention epilogue: two half-passes ----------------
    u16* qkb = (u16*)smem;                       // [112][128] swizzled
    u16(*vt)[64][40] = (u16(*)[64][40])smem;     // phase-3 alias (20480B)
    u16(*spw)[40] = (u16(*)[40])(smem + 28672 + w * 1280);  // this wave's P [16][40]

    int sl = w >> 1, ih = w & 1;    // seq-local 0..3, i-half 0..1
    int rb = sl * 28;
    float slope = exp2f(-0.5f * (float)(head + 1));
    int j0 = lr, j1 = 16 + lr;
    int j0m = j0 % 14, j0d = j0 / 14;
    int j1m = j1 % 14, j1d = j1 / 14;

#pragma unroll 1
    for (int hh = 0; hh < 2; ++hh) {
        // ---- P1: q,k -> swizzled qkb (waves holding rows of this half) ----
        if (wm == hh) {
#pragma unroll
            for (int m = 0; m < 7; m++)
#pragma unroll
                for (int n = 0; n < 3; n++) {
                    int col = wn * 48 + n * 16 + lr;
                    if (col < 128) {
#pragma unroll
                        for (int r = 0; r < 4; ++r) {
                            int lrow = m * 16 + g * 4 + r;
                            qkb[lrow * 128 + (col ^ ((lrow & 7) << 3))] = f2b(acc[m][n][r]);
                        }
                    }
                }
        }
        __syncthreads();

        // ---- P2: QK^T (4 MFMAs) + softmax of 16 rows ----
        f32x4 sc0 = {0.f, 0.f, 0.f, 0.f}, sc1 = {0.f, 0.f, 0.f, 0.f};
#pragma unroll
        for (int c = 0; c < 2; ++c) {
            int u0 = c * 32 + g * 8;
            int arow = rb + ih * 16 + lr;
            int br0 = rb + lr, br1 = rb + 16 + lr;
            bf16x8 aa = *(const bf16x8*)&qkb[arow * 128 + (u0 ^ ((arow & 7) << 3))];
            bf16x8 b0 = *(const bf16x8*)&qkb[br0 * 128 + ((64 + u0) ^ ((br0 & 7) << 3))];
            bf16x8 b1 = *(const bf16x8*)&qkb[br1 * 128 + ((64 + u0) ^ ((br1 & 7) << 3))];
            sc0 = MFMA(aa, b0, sc0);
            sc1 = MFMA(aa, b1, sc1);
        }
#pragma unroll
        for (int r = 0; r < 4; ++r) {
            int i = ih * 16 + g * 4 + r;
            int im = i % 14, id = i / 14;
            float s0 = sc0[r] + slope * (float)(iabs(im - j0m) + iabs(id - j0d));
            float s1 = (j1 < 28)
                           ? sc1[r] + slope * (float)(iabs(im - j1m) + iabs(id - j1d))
                           : -1e30f;
            float mx = fmaxf(s0, s1);
#pragma unroll
            for (int off = 1; off < 16; off <<= 1) mx = fmaxf(mx, __shfl_xor(mx, off));
            float e0 = __expf(s0 - mx), e1 = __expf(s1 - mx);
            float sm = e0 + e1;
#pragma unroll
            for (int off = 1; off < 16; off <<= 1) sm += __shfl_xor(sm, off);
            float inv = 1.f / sm;
            spw[g * 4 + r][lr] = f2b(e0 * inv);
            spw[g * 4 + r][16 + lr] = f2b(e1 * inv);
        }
        __syncthreads();  // all qkb reads done -> region reusable for vt

        // ---- P3: v -> vt over dead qkb ----
        if (t < 256) {
            int s2 = t >> 6, d = t & 63;
#pragma unroll
            for (int j = 28; j < 32; ++j) vt[s2][d][j] = 0;
        }
        if (wm == hh) {
#pragma unroll
            for (int m = 0; m < 7; m++)
#pragma unroll
                for (int n = 0; n < 3; n++) {
                    int col = wn * 48 + n * 16 + lr;
                    if (col >= 128) {
#pragma unroll
                        for (int r = 0; r < 4; ++r) {
                            int lrow = m * 16 + g * 4 + r;
                            int d = col - 128;
                            int s2 = lrow / 28;
                            int j = lrow - s2 * 28;
                            vt[s2][d][j] = f2b(acc[m][n][r]);
                        }
                    }
                }
        }
        __syncthreads();

        // ---- P4: PV (4 MFMAs) + ctx write ----
        bf16x8 pa = *(const bf16x8*)&spw[lr][g * 8];
        f32x4 o[4];
#pragma unroll
        for (int d = 0; d < 4; d++) o[d] = {0.f, 0.f, 0.f, 0.f};
#pragma unroll
        for (int dt = 0; dt < 4; ++dt) {
            bf16x8 bv = *(const bf16x8*)&vt[sl][dt * 16 + lr][g * 8];
            o[dt] = MFMA(pa, bv, o[dt]);
        }
#pragma unroll
        for (int dt = 0; dt < 4; ++dt)
#pragma unroll
            for (int r = 0; r < 4; ++r) {
                int i = ih * 16 + g * 4 + r;
                if (i < 28) {
                    size_t grow = (size_t)bm * 224 + (size_t)hh * 112 + sl * 28 + i;
                    ctx[grow * 1024 + head * 64 + dt * 16 + lr] = f2b(o[dt][r]);
                }
            }
        __syncthreads();  // before next half overwrites qkb
    }
}

// ---------------------------------------------------------------------------
// GEMM (round-1 verbatim): C[M,N] = A[M,1024] bf16 x Bt[N,1024] bf16.
// 128x128 tile, BK=64x2, 256 threads. Used for the output projection.
// ---------------------------------------------------------------------------
template <int OUT_BF16, int RESID>
__global__ __launch_bounds__(256, 2) void gemm_bt(const u16* __restrict__ A,
                                                  const u16* __restrict__ Bt,
                                                  void* __restrict__ Cv,
                                                  const u16* __restrict__ resid,
                                                  int lda, int ldc) {
    __shared__ u16 smem[16384];
    int t = threadIdx.x;

    int nwg = gridDim.x;
    int cpx = nwg >> 3;
    int wg = (blockIdx.x & 7) * cpx + (blockIdx.x >> 3);
    const int sgrp = 448 * 8;
    int sn = wg / sgrp;
    int rem = wg - sn * sgrp;
    int bm = rem >> 3;
    int bn = sn * 8 + (rem & 7);

    const char* Ab = (const char*)A;
    const char* Bb = (const char*)Bt;
    size_t aoffg[4], boffg[4];
#pragma unroll
    for (int i = 0; i < 4; i++) {
        int p = t * 16 + i * 4096;
        int row = p >> 7;
        int colb = (p & 127) ^ ((row & 7) << 4);
        aoffg[i] = (size_t)(bm * 128 + row) * (size_t)lda * 2 + colb;
        boffg[i] = (size_t)(bn * 128 + row) * 2048 + colb;
    }
    char* sA = (char*)smem;
    char* sB = sA + 16384;

    int l = t & 63, w = t >> 6;
    int wm = w >> 1, wn = w & 1, g = l >> 4, lr = l & 15;
    int swz = (lr & 7) << 4;

    f32x4 acc[4][4];
#pragma unroll
    for (int m = 0; m < 4; m++)
#pragma unroll
        for (int n = 0; n < 4; n++) acc[m][n] = {0.f, 0.f, 0.f, 0.f};

    for (int kt = 0; kt < 16; ++kt) {
        int kb = kt * 128;
#pragma unroll
        for (int i = 0; i < 4; i++) GL2LDS(Ab + aoffg[i] + kb, sA + i * 4096 + t * 16);
#pragma unroll
        for (int i = 0; i < 4; i++) GL2LDS(Bb + boffg[i] + kb, sB + i * 4096 + t * 16);
        __syncthreads();
#pragma unroll
        for (int ks = 0; ks < 2; ++ks) {
            bf16x8 af[4], bfv[4];
#pragma unroll
            for (int m = 0; m < 4; m++)
                af[m] = *(const bf16x8*)(sA + (wm * 64 + m * 16 + lr) * 128 +
                                         ((ks * 64 + g * 16) ^ swz));
#pragma unroll
            for (int n = 0; n < 4; n++)
                bfv[n] = *(const bf16x8*)(sB + (wn * 64 + n * 16 + lr) * 128 +
                                          ((ks * 64 + g * 16) ^ swz));
#pragma unroll
            for (int m = 0; m < 4; m++)
#pragma unroll
                for (int n = 0; n < 4; n++)
                    acc[m][n] = MFMA(af[m], bfv[n], acc[m][n]);
        }
        __syncthreads();
    }

    size_t row0 = (size_t)bm * 128 + wm * 64;
    int col0 = bn * 128 + wn * 64;
    if (OUT_BF16) {
        u16* C = (u16*)Cv;
#pragma unroll
        for (int m = 0; m < 4; m++)
#pragma unroll
            for (int n = 0; n < 4; n++)
#pragma unroll
                for (int r = 0; r < 4; r++) {
                    size_t rr = row0 + m * 16 + g * 4 + r;
                    int cc = col0 + n * 16 + lr;
                    C[rr * (size_t)ldc + cc] = f2b(acc[m][n][r]);
                }
    } else {
        float* C = (float*)Cv;
#pragma unroll
        for (int m = 0; m < 4; m++)
#pragma unroll
            for (int n = 0; n < 4; n++)
#pragma unroll
                for (int r = 0; r < 4; r++) {
                    size_t rr = row0 + m * 16 + g * 4 + r;
                    int cc = col0 + n * 16 + lr;
                    float o = acc[m][n][r];
                    if (RESID) o += b2f(resid[rr * 1024 + cc]);
                    C[rr * (size_t)ldc + cc] = o;
                }
    }
}

// ---------------------------------------------------------------------------
extern "C" void kernel_launch(void* const* d_in, const int* in_sizes, int n_in,
                              void* d_out, int out_size, void* d_ws, size_t ws_size,
                              hipStream_t stream) {
    (void)in_sizes; (void)n_in; (void)out_size; (void)ws_size;
    const float* hidden = (const float*)d_in[0];
    const float* wq = (const float*)d_in[1];
    const float* wk = (const float*)d_in[2];
    const float* wv = (const float*)d_in[3];
    const float* wo = (const float*)d_in[4];
    const float* gamma = (const float*)d_in[5];
    const float* beta = (const float*)d_in[6];
    float* out = (float*)d_out;

    char* ws = (char*)d_ws;
    u16* h = (u16*)ws;                                  // 117,440,512 B
    u16* ctx = (u16*)(ws + 117440512);                  // 117,440,512 B
    u16* wqkvt = (u16*)(ws + 234881024);                //   6,291,456 B
    u16* wot = (u16*)(ws + 234881024 + 6291456);        //   2,097,152 B

    wconv_kernel<<<dim3(32, 32, 4), 256, 0, stream>>>(wq, wk, wv, wo, wqkvt, wot);
    ln_kernel<<<14336, 256, 0, stream>>>(hidden, gamma, beta, h);
    fused_qkv_attn<<<4096, 512, 0, stream>>>(h, wqkvt, ctx);
    // ctx is dense [57344][1024] -> lda = 1024
    gemm_bt<0, 1><<<448 * 8, 256, 0, stream>>>(ctx, wot, out, h, 1024, 1024);
}

// Round 11
// 667.740 us; speedup vs baseline: 4.9315x; 1.1635x over previous
//
#include <hip/hip_runtime.h>
#include <hip/hip_bf16.h>

typedef unsigned short u16;
typedef __attribute__((ext_vector_type(8))) short bf16x8;
typedef __attribute__((ext_vector_type(4))) float f32x4;

#define DEVINL __device__ __forceinline__

DEVINL u16 f2b(float f) {
    __hip_bfloat16 h = __float2bfloat16(f);
    return __builtin_bit_cast(u16, h);
}
DEVINL float b2f(u16 u) {
    unsigned int x = ((unsigned int)u) << 16;
    return __builtin_bit_cast(float, x);
}
DEVINL int iabs(int x) { return x < 0 ? -x : x; }
DEVINL f32x4 MFMA(bf16x8 a, bf16x8 b, f32x4 c) {
    return __builtin_amdgcn_mfma_f32_16x16x32_bf16(a, b, c, 0, 0, 0);
}

#define GL2LDS(g, s)                                                                     \
    __builtin_amdgcn_global_load_lds(                                                    \
        (const __attribute__((address_space(1))) unsigned int*)(g),                      \
        (__attribute__((address_space(3))) unsigned int*)(s), 16, 0, 0)

// ---------------------------------------------------------------------------
// Weight convert + transpose.
// z<3 (wq,wk,wv): w[k][n] f32, n = head*64+d  ->  wqkvt[head*192 + z*64 + d][k] bf16
// z==3 (wo): wot[n][k] bf16 (plain B^T)
// ---------------------------------------------------------------------------
__global__ __launch_bounds__(256) void wconv_kernel(const float* __restrict__ wq,
                                                    const float* __restrict__ wk,
                                                    const float* __restrict__ wv,
                                                    const float* __restrict__ wo,
                                                    u16* __restrict__ wqkvt,
                                                    u16* __restrict__ wot) {
    __shared__ float tile[32][33];
    int z = blockIdx.z;
    const float* src = (z == 0) ? wq : (z == 1) ? wk : (z == 2) ? wv : wo;
    int n0 = blockIdx.x * 32, k0 = blockIdx.y * 32;
    int r0 = threadIdx.x >> 5, c = threadIdx.x & 31;
#pragma unroll
    for (int i = 0; i < 4; i++) {
        int r = r0 + i * 8;
        tile[r][c] = src[(size_t)(k0 + r) * 1024 + n0 + c];
    }
    __syncthreads();
    u16* dst = (z < 3) ? wqkvt : wot;
#pragma unroll
    for (int i = 0; i < 4; i++) {
        int r = r0 + i * 8;
        int nn = n0 + r;
        size_t drow = (z < 3) ? ((size_t)(nn >> 6) * 192 + (size_t)z * 64 + (nn & 63))
                              : (size_t)nn;
        dst[drow * 1024 + k0 + c] = f2b(tile[c][r]);
    }
}

// ---------------------------------------------------------------------------
// LayerNorm: one wave per 1024-elem row, output bf16
// ---------------------------------------------------------------------------
__global__ __launch_bounds__(256) void ln_kernel(const float* __restrict__ x,
                                                 const float* __restrict__ gamma,
                                                 const float* __restrict__ beta,
                                                 u16* __restrict__ h) {
    int w = threadIdx.x >> 6, l = threadIdx.x & 63;
    size_t row = (size_t)blockIdx.x * 4 + w;
    const float4* xr = (const float4*)(x + row * 1024);
    float4 v[4];
    float s = 0.f, sq = 0.f;
#pragma unroll
    for (int i = 0; i < 4; i++) {
        v[i] = xr[l + i * 64];
        s += v[i].x + v[i].y + v[i].z + v[i].w;
        sq += v[i].x * v[i].x + v[i].y * v[i].y + v[i].z * v[i].z + v[i].w * v[i].w;
    }
#pragma unroll
    for (int off = 1; off < 64; off <<= 1) {
        s += __shfl_xor(s, off);
        sq += __shfl_xor(sq, off);
    }
    float mu = s * (1.f / 1024.f);
    float var = sq * (1.f / 1024.f) - mu * mu;
    float rstd = rsqrtf(var + 1e-5f);
    const float4* g4 = (const float4*)gamma;
    const float4* b4 = (const float4*)beta;
#pragma unroll
    for (int i = 0; i < 4; i++) {
        float4 g = g4[l + i * 64], b = b4[l + i * 64];
        float y0 = (v[i].x - mu) * rstd * g.x + b.x;
        float y1 = (v[i].y - mu) * rstd * g.y + b.y;
        float y2 = (v[i].z - mu) * rstd * g.z + b.z;
        float y3 = (v[i].w - mu) * rstd * g.w + b.w;
        unsigned int lo = (unsigned int)f2b(y0) | ((unsigned int)f2b(y1) << 16);
        unsigned int hi = (unsigned int)f2b(y2) | ((unsigned int)f2b(y3) << 16);
        uint2 pk;
        pk.x = lo;
        pk.y = hi;
        *(uint2*)(h + row * 1024 + (size_t)(l + i * 64) * 4) = pk;
    }
}

// ---------------------------------------------------------------------------
// Fused QKV-projection + attention (R8 base + minimum-2-phase prefetch).
// One block = 112 rows (4 seqs) x 192 cols (one head's q|k|v). 256 threads,
// 4 waves (1M x 4N), each 112x48 (7x3 frags).
// Double-buffered LDS: 2 x 38912 = 77824 B -> 2 blocks/CU. Per K-tile:
//   issue STAGE(buf^1, kt+1)  [10 global_load_lds]
//   ds_read buf[cur] + 42 MFMA/wave        (prefetch latency hides here)
//   __syncthreads()  [vmcnt drain: prefetch landed; all reads of cur done]
// (T3-minimum recipe; R11 change — R8 was stage->drain->compute, latency
//  fully exposed at 41.7% MfmaUtil.)
// Buffer layout (per buf): sA [0,14336) = 112 rows x 128B (chunk 3 by t<128);
//                          sB [14336,38912) = 192 rows x 128B.
// Attn epilogue (3-phase, in buf0, all GEMM data dead):
//   P1: q,k -> qkb swizzled [112][128] u16 @0 (28672B); barrier.
//   P2: QK^T + softmax; sp[w] u16[32][40] @28672 + w*2560; barrier.
//   P3: v (regs) -> vt u16[4][64][40] @0 over dead qkb; barrier; PV.
// Garbage audit: P2 b1-rows 112..115 land in sp region -> only j>=28 scores,
// masked to -1e30; score rows i>=28 discarded.
// ---------------------------------------------------------------------------
__global__ __launch_bounds__(256, 2) void fused_qkv_attn(const u16* __restrict__ h,
                                                         const u16* __restrict__ wqkvt,
                                                         u16* __restrict__ ctx) {
    __shared__ __align__(16) char smem[77824];
    int t = threadIdx.x;

    int nwg = gridDim.x;  // 8192
    int cpx = nwg >> 3;
    int wg = ((int)blockIdx.x & 7) * cpx + ((int)blockIdx.x >> 3);
    int x = wg >> 10;                // XCD 0..7
    int i0 = wg & 1023;
    int bm = i0 >> 1;                // 0..511 (fast)
    int head = (x << 1) | (i0 & 1);  // 0..15

    // staging: chunk i covers rows srow + i*32 ; 128B rows, XOR swizzle on source
    int p16 = t * 16;
    int srow = p16 >> 7;  // 0..31
    int scolb = (p16 & 127) ^ ((srow & 7) << 4);
    const char* aB = (const char*)h + ((size_t)bm * 112 + srow) * 2048 + scolb;
    const char* bB = (const char*)wqkvt + ((size_t)head * 192 + srow) * 2048 + scolb;

    int l = t & 63, w = t >> 6, g = l >> 4, lr = l & 15;
    int swz = (lr & 7) << 4;

    f32x4 acc[7][3];
#pragma unroll
    for (int m = 0; m < 7; m++)
#pragma unroll
        for (int n = 0; n < 3; n++) acc[m][n] = {0.f, 0.f, 0.f, 0.f};

// stage K-tile (byte offset kb) into buffer base d
#define STAGE(d, kb)                                                                     \
    do {                                                                                 \
        char* dA = (d);                                                                  \
        _Pragma("unroll") for (int i = 0; i < 3; i++)                                    \
            GL2LDS(aB + (size_t)i * 65536 + (kb), dA + i * 4096 + p16);                  \
        if (t < 128) GL2LDS(aB + (size_t)3 * 65536 + (kb), dA + 3 * 4096 + p16);         \
        char* dB = (d) + 14336;                                                          \
        _Pragma("unroll") for (int i = 0; i < 6; i++)                                    \
            GL2LDS(bB + (size_t)i * 65536 + (kb), dB + i * 4096 + p16);                  \
    } while (0)

    // prologue: stage tile 0 into buf 0
    STAGE(smem, 0);
    __syncthreads();

#pragma unroll 1
    for (int kt = 0; kt < 16; ++kt) {
        char* bufc = smem + (kt & 1) * 38912;
        char* bufn = smem + ((kt & 1) ^ 1) * 38912;
        // issue next-tile prefetch BEFORE compute (latency hides under MFMA)
        if (kt < 15) STAGE(bufn, (kt + 1) * 128);

        const char* sA = bufc;
        const char* sB = bufc + 14336;
#pragma unroll
        for (int ks = 0; ks < 2; ++ks) {
            bf16x8 af[7], bfv[3];
#pragma unroll
            for (int m = 0; m < 7; m++)
                af[m] = *(const bf16x8*)(sA + (m * 16 + lr) * 128 + ((ks * 64 + g * 16) ^ swz));
#pragma unroll
            for (int n = 0; n < 3; n++)
                bfv[n] = *(const bf16x8*)(sB + (w * 48 + n * 16 + lr) * 128 +
                                          ((ks * 64 + g * 16) ^ swz));
#pragma unroll
            for (int m = 0; m < 7; m++)
#pragma unroll
                for (int n = 0; n < 3; n++) acc[m][n] = MFMA(af[m], bfv[n], acc[m][n]);
        }
        __syncthreads();  // vmcnt drain (prefetch landed) + all reads of cur done
    }
#undef STAGE

    // ---------------- epilogue phase 1: q,k -> swizzled qkb (buf0) ----------------
    u16* qkb = (u16*)smem;                                    // [112][128] swizzled
    u16(*sp)[40] = (u16(*)[40])(smem + 28672 + w * 2560);     // per-wave P
    u16(*vt)[64][40] = (u16(*)[64][40])smem;                  // phase-3 alias

#pragma unroll
    for (int m = 0; m < 7; m++)
#pragma unroll
        for (int n = 0; n < 3; n++) {
            int col = w * 48 + n * 16 + lr;
            if (col < 128) {
#pragma unroll
                for (int r = 0; r < 4; ++r) {
                    int row = m * 16 + g * 4 + r;
                    qkb[row * 128 + (col ^ ((row & 7) << 3))] = f2b(acc[m][n][r]);
                }
            }
        }
    __syncthreads();

    // ---------------- phase 2: QK^T + softmax ----------------
    int rbase = w * 28;
    f32x4 sc[2][2];
#pragma unroll
    for (int a = 0; a < 2; a++)
#pragma unroll
        for (int c = 0; c < 2; c++) sc[a][c] = {0.f, 0.f, 0.f, 0.f};
#pragma unroll
    for (int c = 0; c < 2; c++) {
        int r0 = rbase + lr, r1 = rbase + 16 + lr;
        int u0 = c * 32 + g * 8;
        bf16x8 a0 = *(const bf16x8*)&qkb[r0 * 128 + (u0 ^ ((r0 & 7) << 3))];
        bf16x8 a1 = *(const bf16x8*)&qkb[r1 * 128 + (u0 ^ ((r1 & 7) << 3))];
        bf16x8 b0 = *(const bf16x8*)&qkb[r0 * 128 + ((64 + u0) ^ ((r0 & 7) << 3))];
        bf16x8 b1 = *(const bf16x8*)&qkb[r1 * 128 + ((64 + u0) ^ ((r1 & 7) << 3))];
        sc[0][0] = MFMA(a0, b0, sc[0][0]);
        sc[0][1] = MFMA(a0, b1, sc[0][1]);
        sc[1][0] = MFMA(a1, b0, sc[1][0]);
        sc[1][1] = MFMA(a1, b1, sc[1][1]);
    }

    float slope = exp2f(-0.5f * (float)(head + 1));
    int j0 = lr, j1 = 16 + lr;
    int j0m = j0 % 14, j0d = j0 / 14;
    int j1m = j1 % 14, j1d = j1 / 14;
#pragma unroll
    for (int it = 0; it < 2; ++it) {
#pragma unroll
        for (int r = 0; r < 4; ++r) {
            int i = it * 16 + g * 4 + r;
            int im = i % 14, id = i / 14;
            float s0 = sc[it][0][r] + slope * (float)(iabs(im - j0m) + iabs(id - j0d));
            float s1 = (j1 < 28)
                           ? sc[it][1][r] + slope * (float)(iabs(im - j1m) + iabs(id - j1d))
                           : -1e30f;
            float mx = fmaxf(s0, s1);
#pragma unroll
            for (int off = 1; off < 16; off <<= 1) mx = fmaxf(mx, __shfl_xor(mx, off));
            float e0 = __expf(s0 - mx), e1 = __expf(s1 - mx);
            float sm = e0 + e1;
#pragma unroll
            for (int off = 1; off < 16; off <<= 1) sm += __shfl_xor(sm, off);
            float inv = 1.f / sm;
            sp[i][lr] = f2b(e0 * inv);
            sp[i][16 + lr] = f2b(e1 * inv);
        }
    }
    __syncthreads();  // all QK^T reads of qkb done -> q/k region reusable

    // ---------------- phase 3: v -> vt, then PV ----------------
    {
        int s2 = t >> 6, d = t & 63;
#pragma unroll
        for (int j = 28; j < 32; ++j) vt[s2][d][j] = 0;
    }
#pragma unroll
    for (int m = 0; m < 7; m++)
#pragma unroll
        for (int n = 0; n < 3; n++) {
            int col = w * 48 + n * 16 + lr;
            if (col >= 128) {
#pragma unroll
                for (int r = 0; r < 4; ++r) {
                    int row = m * 16 + g * 4 + r;
                    int d = col - 128;
                    int s2 = row / 28;
                    int j = row - s2 * 28;
                    vt[s2][d][j] = f2b(acc[m][n][r]);
                }
            }
        }
    __syncthreads();

    // PV (sp same-wave RAW, HW-ordered; vt barrier-covered)
    bf16x8 pa0 = *(const bf16x8*)&sp[lr][g * 8];
    bf16x8 pa1 = *(const bf16x8*)&sp[16 + lr][g * 8];
    f32x4 o[2][4];
#pragma unroll
    for (int a = 0; a < 2; a++)
#pragma unroll
        for (int d = 0; d < 4; d++) o[a][d] = {0.f, 0.f, 0.f, 0.f};
#pragma unroll
    for (int dt = 0; dt < 4; ++dt) {
        bf16x8 bv = *(const bf16x8*)&vt[w][dt * 16 + lr][g * 8];
        o[0][dt] = MFMA(pa0, bv, o[0][dt]);
        o[1][dt] = MFMA(pa1, bv, o[1][dt]);
    }
#pragma unroll
    for (int it = 0; it < 2; ++it)
#pragma unroll
        for (int dt = 0; dt < 4; ++dt)
#pragma unroll
            for (int r = 0; r < 4; ++r) {
                int i = it * 16 + g * 4 + r;
                if (i < 28) {
                    size_t off =
                        ((size_t)(bm * 4 + w) * 28 + i) * 1024 + head * 64 + dt * 16 + lr;
                    ctx[off] = f2b(o[it][dt][r]);
                }
            }
}

// ---------------------------------------------------------------------------
// GEMM (round-1 verbatim): C[M,N] = A[M,1024] bf16 x Bt[N,1024] bf16.
// 128x128 tile, BK=64x2, 256 threads. Used for the output projection.
// ---------------------------------------------------------------------------
template <int OUT_BF16, int RESID>
__global__ __launch_bounds__(256, 2) void gemm_bt(const u16* __restrict__ A,
                                                  const u16* __restrict__ Bt,
                                                  void* __restrict__ Cv,
                                                  const u16* __restrict__ resid,
                                                  int lda, int ldc) {
    __shared__ u16 smem[16384];
    int t = threadIdx.x;

    int nwg = gridDim.x;
    int cpx = nwg >> 3;
    int wg = (blockIdx.x & 7) * cpx + (blockIdx.x >> 3);
    const int sgrp = 448 * 8;
    int sn = wg / sgrp;
    int rem = wg - sn * sgrp;
    int bm = rem >> 3;
    int bn = sn * 8 + (rem & 7);

    const char* Ab = (const char*)A;
    const char* Bb = (const char*)Bt;
    size_t aoffg[4], boffg[4];
#pragma unroll
    for (int i = 0; i < 4; i++) {
        int p = t * 16 + i * 4096;
        int row = p >> 7;
        int colb = (p & 127) ^ ((row & 7) << 4);
        aoffg[i] = (size_t)(bm * 128 + row) * (size_t)lda * 2 + colb;
        boffg[i] = (size_t)(bn * 128 + row) * 2048 + colb;
    }
    char* sA = (char*)smem;
    char* sB = sA + 16384;

    int l = t & 63, w = t >> 6;
    int wm = w >> 1, wn = w & 1, g = l >> 4, lr = l & 15;
    int swz = (lr & 7) << 4;

    f32x4 acc[4][4];
#pragma unroll
    for (int m = 0; m < 4; m++)
#pragma unroll
        for (int n = 0; n < 4; n++) acc[m][n] = {0.f, 0.f, 0.f, 0.f};

    for (int kt = 0; kt < 16; ++kt) {
        int kb = kt * 128;
#pragma unroll
        for (int i = 0; i < 4; i++) GL2LDS(Ab + aoffg[i] + kb, sA + i * 4096 + t * 16);
#pragma unroll
        for (int i = 0; i < 4; i++) GL2LDS(Bb + boffg[i] + kb, sB + i * 4096 + t * 16);
        __syncthreads();
#pragma unroll
        for (int ks = 0; ks < 2; ++ks) {
            bf16x8 af[4], bfv[4];
#pragma unroll
            for (int m = 0; m < 4; m++)
                af[m] = *(const bf16x8*)(sA + (wm * 64 + m * 16 + lr) * 128 +
                                         ((ks * 64 + g * 16) ^ swz));
#pragma unroll
            for (int n = 0; n < 4; n++)
                bfv[n] = *(const bf16x8*)(sB + (wn * 64 + n * 16 + lr) * 128 +
                                          ((ks * 64 + g * 16) ^ swz));
#pragma unroll
            for (int m = 0; m < 4; m++)
#pragma unroll
                for (int n = 0; n < 4; n++)
                    acc[m][n] = MFMA(af[m], bfv[n], acc[m][n]);
        }
        __syncthreads();
    }

    size_t row0 = (size_t)bm * 128 + wm * 64;
    int col0 = bn * 128 + wn * 64;
    if (OUT_BF16) {
        u16* C = (u16*)Cv;
#pragma unroll
        for (int m = 0; m < 4; m++)
#pragma unroll
            for (int n = 0; n < 4; n++)
#pragma unroll
                for (int r = 0; r < 4; r++) {
                    size_t rr = row0 + m * 16 + g * 4 + r;
                    int cc = col0 + n * 16 + lr;
                    C[rr * (size_t)ldc + cc] = f2b(acc[m][n][r]);
                }
    } else {
        float* C = (float*)Cv;
#pragma unroll
        for (int m = 0; m < 4; m++)
#pragma unroll
            for (int n = 0; n < 4; n++)
#pragma unroll
                for (int r = 0; r < 4; r++) {
                    size_t rr = row0 + m * 16 + g * 4 + r;
                    int cc = col0 + n * 16 + lr;
                    float o = acc[m][n][r];
                    if (RESID) o += b2f(resid[rr * 1024 + cc]);
                    C[rr * (size_t)ldc + cc] = o;
                }
    }
}

// ---------------------------------------------------------------------------
extern "C" void kernel_launch(void* const* d_in, const int* in_sizes, int n_in,
                              void* d_out, int out_size, void* d_ws, size_t ws_size,
                              hipStream_t stream) {
    (void)in_sizes; (void)n_in; (void)out_size; (void)ws_size;
    const float* hidden = (const float*)d_in[0];
    const float* wq = (const float*)d_in[1];
    const float* wk = (const float*)d_in[2];
    const float* wv = (const float*)d_in[3];
    const float* wo = (const float*)d_in[4];
    const float* gamma = (const float*)d_in[5];
    const float* beta = (const float*)d_in[6];
    float* out = (float*)d_out;

    char* ws = (char*)d_ws;
    u16* h = (u16*)ws;                                  // 117,440,512 B
    u16* ctx = (u16*)(ws + 117440512);                  // 117,440,512 B
    u16* wqkvt = (u16*)(ws + 234881024);                //   6,291,456 B
    u16* wot = (u16*)(ws + 234881024 + 6291456);        //   2,097,152 B

    wconv_kernel<<<dim3(32, 32, 4), 256, 0, stream>>>(wq, wk, wv, wo, wqkvt, wot);
    ln_kernel<<<14336, 256, 0, stream>>>(hidden, gamma, beta, h);
    fused_qkv_attn<<<8192, 256, 0, stream>>>(h, wqkvt, ctx);
    // ctx is dense [57344][1024] -> lda = 1024
    gemm_bt<0, 1><<<448 * 8, 256, 0, stream>>>(ctx, wot, out, h, 1024, 1024);
}